// Round 7
// baseline (101.290 us; speedup 1.0000x reference)
//
#include <hip/hip_runtime.h>
#include <math.h>
#include <stdint.h>

#define N_ANCH 49104
#define NCLS 80
#define KDET 100
#define CAP 256              // sort size == TPB; candidates per chunk
#define TPB 256
#define NBINS 1024
#define NBLK 512             // collect blocks (2/CU)
#define SUBCAP 16            // slots per (class, block) sub-list (mean ~0.4, P(>16) ~ 0)
#define THETA 0.996090f      // targets ~192 candidates/class; exact fallback if wrong
#define QTOT (N_ANCH * NCLS / 4)   // 982080 float4 quads
#define JMAX 16              // Jacobi round bound (serial fallback if exceeded)

// ws layout: list [NCLS*NBLK*SUBCAP u64] | subcnt [NCLS*NBLK int]
#define LIST_ELEMS ((size_t)NCLS * NBLK * SUBCAP)
#define SUBCNT_OFF (LIST_ELEMS * 8)
#define WS_NEED (SUBCNT_OFF + (size_t)NCLS * NBLK * 4)

// ---------------- 512 blocks: batched grid-stride read of [N,C], LDS counters, NO global atomics ----------------
__device__ __forceinline__ void collect_quad(int q, float4 v, int* lcnt,
                                             uint64_t* __restrict__ list, int blk) {
    const int n = q / 20;            // anchor: 4q/80
    const int c0 = 4 * (q % 20);     // first class of quad (80 % 4 == 0: never crosses anchors)
    float ss[4] = {v.x, v.y, v.z, v.w};
#pragma unroll
    for (int u = 0; u < 4; u++) {
        float s = ss[u];
        if (s > THETA) {
            int c = c0 + u;
            int p = atomicAdd(&lcnt[c], 1);              // LDS atomic only
            if (p < SUBCAP) {
                uint32_t bits = __float_as_uint(s);      // s>0: bit order == value order
                list[((size_t)c * NBLK + blk) * SUBCAP + p] =
                    ((uint64_t)(~bits) << 16) | (uint64_t)n;   // score desc, anchor asc
            }
        }
    }
}

__global__ __launch_bounds__(TPB) void collect_kernel(const float* __restrict__ scores,
                                                      uint64_t* __restrict__ list,
                                                      int* __restrict__ subcnt) {
    const int blk = blockIdx.x, tid = threadIdx.x;
    __shared__ int lcnt[NCLS];
    for (int c = tid; c < NCLS; c += TPB) lcnt[c] = 0;
    __syncthreads();
    const float4* sc4 = (const float4*)scores;
    const int stride = NBLK * TPB;                       // 131072
    int q = blk * TPB + tid;
    for (; q + 3 * stride < QTOT; q += 4 * stride) {     // 4 independent loads in flight
        float4 v0 = sc4[q], v1 = sc4[q + stride], v2 = sc4[q + 2 * stride], v3 = sc4[q + 3 * stride];
        collect_quad(q, v0, lcnt, list, blk);
        collect_quad(q + stride, v1, lcnt, list, blk);
        collect_quad(q + 2 * stride, v2, lcnt, list, blk);
        collect_quad(q + 3 * stride, v3, lcnt, list, blk);
    }
    for (; q < QTOT; q += stride) collect_quad(q, sc4[q], lcnt, list, blk);
    __syncthreads();
    for (int c = tid; c < NCLS; c += TPB) subcnt[c * NBLK + blk] = lcnt[c];  // raw (overflow detectable)
}

// ---------------- shared state for the per-class core ----------------
struct ChunkShared {
    uint64_t keys[CAP];
    float4   bxu[CAP];                 // boxes at UNSORTED slot (prefetched during sort)
    float4   rbox[CAP];                // boxes in sorted (rank) order
    float    ra[CAP], rs[CAP];
    uint64_t smat[CAP * (CAP / 64)];   // ST: column i = "who suppresses i" (j < i), words 0..i/64
    uint64_t lwbuf[CAP / 64];          // alive (post filter-vs-kept) ballot words
    uint64_t s_kw[CAP / 64];           // kept ballot words (Jacobi / result)
    int      s_cw[4];                  // per-wave change flags
    float4   kbox[KDET];
    float    kar[KDET], ksc[KDET];
};

// Keys: (~score_bits)<<24 | anchor<<8 | slot. Anchors unique per class => slot bits never affect order.
// register bitonic sort (box loads in flight) -> LDS permute -> filter-vs-kept -> ST ballots ->
// Jacobi fixpoint -> parallel extract. Exact (unique fixpoint == serial greedy; serial fallback kept).
__device__ __forceinline__ int process_chunk(ChunkShared& S, int tid, int M, int kc0,
                                             const float* __restrict__ boxes) {
    if (M <= 0) return kc0;                       // uniform across block
    const int lane = tid & 63, wid = tid >> 6;
    uint64_t key = (tid < M) ? S.keys[tid] : ~0ull;
    // ---- issue box load for MY (unsorted) slot before sorting; latency hides under the sort ----
    float4 mybox;
    if (tid < M) {
        int n = (int)((key >> 8) & 0xFFFFull);
        mybox = *(const float4*)(boxes + (size_t)n * 4);
    }
    // ---- bitonic sort, keys in registers; LDS staging only for cross-wave strides (j>=64) ----
    for (int k = 2; k <= CAP; k <<= 1) {
        for (int j = k >> 1; j > 0; j >>= 1) {
            uint64_t other;
            if (j >= 64) {
                __syncthreads();
                S.keys[tid] = key;
                __syncthreads();
                other = S.keys[tid ^ j];
            } else {
                other = (uint64_t)__shfl_xor((unsigned long long)key, j, 64);
            }
            const bool up = ((tid & k) == 0);
            const bool lower = ((tid & j) == 0);
            const uint64_t mn = key < other ? key : other;
            const uint64_t mx = key < other ? other : key;
            key = (lower == up) ? mn : mx;
        }
    }
    // ---- land prefetched box at unsorted slot, then permute to sorted order via LDS ----
    if (tid < M) S.bxu[tid] = mybox;              // waitcnt lands here (post-sort)
    __syncthreads();
    if (tid < M) {
        int slot = (int)(key & 0xFFull);          // pre-sort position of my sorted key
        float4 bx = S.bxu[slot];
        S.rbox[tid] = bx;
        S.ra[tid] = (bx.z - bx.x) * (bx.w - bx.y);
        S.rs[tid] = __uint_as_float(~((uint32_t)(key >> 24)));
    }
    __syncthreads();
    // ---- filter vs previously-kept boxes (exact chunk continuation) ----
    bool alive = (tid < M);
    if (alive && kc0 > 0) {
        float4 b = S.rbox[tid];
        float arb = S.ra[tid];
        for (int k2 = 0; k2 < kc0; k2++) {
            float4 kb = S.kbox[k2];
            float ix1 = fmaxf(kb.x, b.x), iy1 = fmaxf(kb.y, b.y);
            float ix2 = fminf(kb.z, b.z), iy2 = fminf(kb.w, b.w);
            float inter = fmaxf(ix2 - ix1, 0.0f) * fmaxf(iy2 - iy1, 0.0f);
            float iou = inter / (S.kar[k2] + arb - inter + 1e-8f);
            if (iou > 0.5f) { alive = false; break; }
        }
    }
    {
        uint64_t bal = __ballot(alive);
        if (lane == 0) S.lwbuf[wid] = bal;
    }
    __syncthreads();
    // ---- ST bitmatrix: column i = suppressors j<i, via ballots; (vw,ws) word-pairs over waves ----
    for (int p = wid; p < 10; p += 4) {
        const int vw = (int)((0x3333222110ull >> (4 * p)) & 0xF);   // victim word
        const int ws = (int)((0x3210210100ull >> (4 * p)) & 0xF);   // suppressor word (ws <= vw)
        const int i0 = vw << 6;
        if (i0 >= M) continue;
        const int i1 = min(M, i0 + 64);
        const int jj = (ws << 6) + lane;
        float4 bj = S.rbox[jj];                    // jj>=M possible only when ws==vw: masked by jj<i
        float arj = S.ra[jj];
        for (int i = i0; i < i1; i++) {
            bool bit = false;
            if (jj < i) {
                float4 bi = S.rbox[i];             // same-address LDS broadcast
                float ari = S.ra[i];
                float ix1 = fmaxf(bj.x, bi.x), iy1 = fmaxf(bj.y, bi.y);
                float ix2 = fminf(bj.z, bi.z), iy2 = fminf(bj.w, bi.w);
                float inter = fmaxf(ix2 - ix1, 0.0f) * fmaxf(iy2 - iy1, 0.0f);
                float iou = inter / (arj + ari - inter + 1e-8f);   // fp-add commutative: == ref order
                bit = iou > 0.5f;
            }
            uint64_t bb = __ballot(bit);
            if (lane == 0) S.smat[((size_t)i << 2) + ws] = bb;
        }
    }
    __syncthreads();
    // ---- my ST column into registers (words 0..wid written this chunk; others stale -> 0) ----
    uint64_t st0 = 0, st1 = 0, st2 = 0, st3 = 0;
    if (tid < M) {
        st0 = S.smat[((size_t)tid << 2) + 0];
        if (wid >= 1) st1 = S.smat[((size_t)tid << 2) + 1];
        if (wid >= 2) st2 = S.smat[((size_t)tid << 2) + 2];
        if (wid >= 3) st3 = S.smat[((size_t)tid << 2) + 3];
    }
    // ---- Jacobi to fixpoint: zero memory-dependent chain; ~2-4 rounds on sparse data ----
    bool kept = alive;
    bool converged = false;
    for (int it = 0; it < JMAX; it++) {
        uint64_t kb = __ballot(kept);
        if (lane == 0) S.s_kw[wid] = kb;
        __syncthreads();
        const uint64_t k0 = S.s_kw[0], k1 = S.s_kw[1], k2 = S.s_kw[2], k3 = S.s_kw[3];
        const bool sup = ((k0 & st0) | (k1 & st1) | (k2 & st2) | (k3 & st3)) != 0ull;
        const bool nk = alive && !sup;
        uint64_t cb = __ballot(nk != kept);
        if (lane == 0) S.s_cw[wid] = (cb != 0ull) ? 1 : 0;
        kept = nk;
        __syncthreads();
        if ((S.s_cw[0] | S.s_cw[1] | S.s_cw[2] | S.s_cw[3]) == 0) { converged = true; break; }
        // on break: s_kw holds ballot of pre-update kept == final kept (no change occurred)
    }
    if (!converged) {                              // exact serial fallback (pathological chains only)
        if (tid == 0) {
            uint64_t lv[4] = {S.lwbuf[0], S.lwbuf[1], S.lwbuf[2], S.lwbuf[3]};
            uint64_t kw[4] = {0, 0, 0, 0};
            for (int i = 0; i < M; i++) {
                const int w = i >> 6, b = i & 63;
                if (!((lv[w] >> b) & 1ull)) continue;
                const uint64_t* row = &S.smat[(size_t)i << 2];
                uint64_t sup = kw[0] & row[0];
                if (w >= 1) sup |= kw[1] & row[1];
                if (w >= 2) sup |= kw[2] & row[2];
                if (w >= 3) sup |= kw[3] & row[3];
                if (!sup) kw[w] |= 1ull << b;
            }
            S.s_kw[0] = kw[0]; S.s_kw[1] = kw[1]; S.s_kw[2] = kw[2]; S.s_kw[3] = kw[3];
        }
        __syncthreads();
    }
    // ---- parallel extraction in greedy (index) order ----
    const uint64_t k0 = S.s_kw[0], k1 = S.s_kw[1], k2 = S.s_kw[2], k3 = S.s_kw[3];
    const int total = __popcll(k0) + __popcll(k1) + __popcll(k2) + __popcll(k3);
    const uint64_t mykw = (wid == 0) ? k0 : (wid == 1) ? k1 : (wid == 2) ? k2 : k3;
    if (tid < M && ((mykw >> lane) & 1ull)) {
        int rank = __popcll(mykw & ((1ull << lane) - 1ull));
        if (wid > 0) rank += __popcll(k0);
        if (wid > 1) rank += __popcll(k1);
        if (wid > 2) rank += __popcll(k2);
        const int r = kc0 + rank;
        if (r < KDET) { S.kbox[r] = S.rbox[tid]; S.kar[r] = S.ra[tid]; S.ksc[r] = S.rs[tid]; }
    }
    __syncthreads();
    return min(kc0 + total, KDET);
}

// ---------------- 80 blocks: wave-prefix gather (2 sub-lists/thread) -> core; exact fallback ----------------
__global__ __launch_bounds__(TPB) void nms_final(const float* __restrict__ scores,
                                                 const float* __restrict__ boxes,
                                                 const uint64_t* __restrict__ list,
                                                 const int* __restrict__ subcnt,
                                                 int use_lists,
                                                 float* __restrict__ out) {
    const int c = blockIdx.x, tid = threadIdx.x;
    const int lane = tid & 63, wid = tid >> 6;
    __shared__ ChunkShared S;
    __shared__ int hist[NBINS];
    __shared__ int s_wtot[4];
    __shared__ int s_ov, s_cnt, s_lo;

    int kc = 0;
    bool fast = false;
    if (use_lists) {
        if (tid == 0) s_ov = 0;
        __syncthreads();
        const int raw0 = subcnt[c * NBLK + tid];
        const int raw1 = subcnt[c * NBLK + TPB + tid];
        if (raw0 > SUBCAP || raw1 > SUBCAP) atomicOr(&s_ov, 1);
        const int v0 = min(raw0, SUBCAP), v1 = min(raw1, SUBCAP);
        const int v = v0 + v1;
        int incl = v;                              // wave-inclusive scan via shuffles
        for (int d = 1; d < 64; d <<= 1) {
            int o = __shfl_up(incl, d, 64);
            if (lane >= d) incl += o;
        }
        if (lane == 63) s_wtot[wid] = incl;
        __syncthreads();
        int woff = 0;
        for (int w = 0; w < wid; w++) woff += s_wtot[w];
        const int off = woff + incl - v;           // exclusive offset (sub-list order arbitrary: sort fixes it)
        const int M0 = s_wtot[0] + s_wtot[1] + s_wtot[2] + s_wtot[3];
        fast = (s_ov == 0) && (M0 <= CAP);
        if (fast) {
            const uint64_t* src0 = list + ((size_t)c * NBLK + tid) * SUBCAP;
            const uint64_t* src1 = list + ((size_t)c * NBLK + TPB + tid) * SUBCAP;
            for (int k = 0; k < v0; k++) S.keys[off + k]      = (src0[k] << 8) | (uint64_t)(off + k);
            for (int k = 0; k < v1; k++) S.keys[off + v0 + k] = (src1[k] << 8) | (uint64_t)(off + v0 + k);
        }
        __syncthreads();
        if (fast) kc = process_chunk(S, tid, M0, 0, boxes);
    }
    if (kc < KDET) {
        // exact slow path: strided column reads; partition s <= THETA iff fast chunk consumed (s > THETA)
        const float hicut = fast ? THETA : 3.0e38f;
        if (!fast) kc = 0;
        for (int b = tid; b < NBINS; b += TPB) hist[b] = 0;
        __syncthreads();
        for (int n = tid; n < N_ANCH; n += TPB) {
            float s = scores[(size_t)n * NCLS + c];
            if (s > 0.05f && s <= hicut) {
                int b = (int)(s * 1024.0f);
                b = b < 0 ? 0 : (b > NBINS - 1 ? NBINS - 1 : b);
                atomicAdd(&hist[b], 1);
            }
        }
        __syncthreads();
        int hi = NBINS;
        while (hi > 0 && kc < KDET) {
            if (tid == 0) {
                int lo = hi, tot = 0;
                while (lo > 0 && tot + hist[lo - 1] <= CAP) { lo--; tot += hist[lo]; }
                if (lo == hi) lo = hi - 1;         // oversized single bin: truncate (not hit here)
                s_lo = lo; s_cnt = 0;
            }
            __syncthreads();
            const int lo = s_lo;
            for (int n = tid; n < N_ANCH; n += TPB) {
                float s = scores[(size_t)n * NCLS + c];
                if (s > 0.05f && s <= hicut) {
                    int b = (int)(s * 1024.0f);
                    b = b < 0 ? 0 : (b > NBINS - 1 ? NBINS - 1 : b);
                    if (b >= lo && b < hi) {
                        int p = atomicAdd(&s_cnt, 1);
                        if (p < CAP) {
                            uint32_t bits = __float_as_uint(s);
                            S.keys[p] = ((uint64_t)(~bits) << 24) | ((uint64_t)n << 8) | (uint64_t)p;
                        }
                    }
                }
            }
            __syncthreads();
            const int M2 = min(s_cnt, CAP);
            kc = process_chunk(S, tid, M2, kc, boxes);
            hi = lo;
        }
    }
    __syncthreads();

    // outputs: [scores | classes | boxes | valids] as float32
    float* o_sc = out;
    float* o_cl = out + NCLS * KDET;
    float* o_bx = out + 2 * NCLS * KDET;
    float* o_va = out + 6 * NCLS * KDET;
    for (int k = tid; k < KDET; k += TPB) {
        bool valid = k < kc;
        o_sc[c * KDET + k] = valid ? S.ksc[k] : 0.0f;
        o_cl[c * KDET + k] = (float)c;
        o_va[c * KDET + k] = valid ? 1.0f : 0.0f;
        float4 bo;
        if (valid) bo = S.kbox[k];
        else { bo.x = 0.0f; bo.y = 0.0f; bo.z = 0.0f; bo.w = 0.0f; }
        *(float4*)(o_bx + ((size_t)(c * KDET + k)) * 4) = bo;
    }
}

extern "C" void kernel_launch(void* const* d_in, const int* in_sizes, int n_in,
                              void* d_out, int out_size, void* d_ws, size_t ws_size,
                              hipStream_t stream) {
    const float* scores = (const float*)d_in[0];   // [N, C] f32
    const float* boxes  = (const float*)d_in[1];   // [N, 4] f32
    float* out = (float*)d_out;                    // 56000 f32: scores|classes|boxes|valids

    uint64_t* list   = (uint64_t*)d_ws;
    int*      subcnt = (int*)((char*)d_ws + SUBCNT_OFF);
    const int use_lists = (ws_size >= WS_NEED) ? 1 : 0;

    if (use_lists) {
        collect_kernel<<<NBLK, TPB, 0, stream>>>(scores, list, subcnt);
    }
    nms_final<<<NCLS, TPB, 0, stream>>>(scores, boxes, list, subcnt, use_lists, out);
}

// Round 8
// 100.397 us; speedup vs baseline: 1.0089x; 1.0089x over previous
//
#include <hip/hip_runtime.h>
#include <math.h>
#include <stdint.h>

#define N_ANCH 49104
#define NCLS 80
#define KDET 100
#define CAP 256              // chunk size == TPB
#define TPB 256
#define NBINS 1024
#define NBLK 512             // collect blocks (2/CU)
#define SUBCAP 16            // slots per (class, block) sub-list (mean ~0.4, P(>16) ~ 0)
#define THETA 0.996090f      // targets ~192 candidates/class; exact fallback if wrong
#define QTOT (N_ANCH * NCLS / 4)   // 982080 float4 quads
#define JMAX 16              // Jacobi round bound (serial fallback if exceeded)
// pad keys: unique, strictly greater than any real key (real <= 0xC2B33332FFFF for s>0.05)
#define PADKEY(t) ((0xFFFFFFFFull << 16) | (uint64_t)(t))

// ws layout: list [NCLS*NBLK*SUBCAP u64] | subcnt [NCLS*NBLK int]
#define LIST_ELEMS ((size_t)NCLS * NBLK * SUBCAP)
#define SUBCNT_OFF (LIST_ELEMS * 8)
#define WS_NEED (SUBCNT_OFF + (size_t)NCLS * NBLK * 4)

// ---------------- 512 blocks: batched grid-stride read of [N,C], LDS counters, NO global atomics ----------------
__device__ __forceinline__ void collect_quad(int q, float4 v, int* lcnt,
                                             uint64_t* __restrict__ list, int blk) {
    const int n = q / 20;            // anchor: 4q/80
    const int c0 = 4 * (q % 20);     // first class of quad (80 % 4 == 0: never crosses anchors)
    float ss[4] = {v.x, v.y, v.z, v.w};
#pragma unroll
    for (int u = 0; u < 4; u++) {
        float s = ss[u];
        if (s > THETA) {
            int c = c0 + u;
            int p = atomicAdd(&lcnt[c], 1);              // LDS atomic only
            if (p < SUBCAP) {
                uint32_t bits = __float_as_uint(s);      // s>0: bit order == value order
                list[((size_t)c * NBLK + blk) * SUBCAP + p] =
                    ((uint64_t)(~bits) << 16) | (uint64_t)n;   // score desc, anchor asc
            }
        }
    }
}

__global__ __launch_bounds__(TPB) void collect_kernel(const float* __restrict__ scores,
                                                      uint64_t* __restrict__ list,
                                                      int* __restrict__ subcnt) {
    const int blk = blockIdx.x, tid = threadIdx.x;
    __shared__ int lcnt[NCLS];
    for (int c = tid; c < NCLS; c += TPB) lcnt[c] = 0;
    __syncthreads();
    const float4* sc4 = (const float4*)scores;
    const int stride = NBLK * TPB;                       // 131072
    int q = blk * TPB + tid;
    for (; q + 3 * stride < QTOT; q += 4 * stride) {     // 4 independent loads in flight
        float4 v0 = sc4[q], v1 = sc4[q + stride], v2 = sc4[q + 2 * stride], v3 = sc4[q + 3 * stride];
        collect_quad(q, v0, lcnt, list, blk);
        collect_quad(q + stride, v1, lcnt, list, blk);
        collect_quad(q + 2 * stride, v2, lcnt, list, blk);
        collect_quad(q + 3 * stride, v3, lcnt, list, blk);
    }
    for (; q < QTOT; q += stride) collect_quad(q, sc4[q], lcnt, list, blk);
    __syncthreads();
    for (int c = tid; c < NCLS; c += TPB) subcnt[c * NBLK + blk] = lcnt[c];  // raw (overflow detectable)
}

// ---------------- shared state for the per-class core ----------------
struct ChunkShared {
    uint64_t keys[CAP];                // real keys at [0,M), PADKEY elsewhere (all unique)
    float4   rbox[CAP];                // boxes in sorted (rank) order
    float    ra[CAP], rs[CAP];
    uint64_t smat[CAP * (CAP / 64)];   // ST: column i = "who suppresses i" (j < i), words 0..i/64
    uint64_t lwbuf[CAP / 64];          // alive (post filter-vs-kept) ballot words
    uint64_t s_kw[CAP / 64];           // kept ballot words (Jacobi / result)
    int      s_cw[4];                  // per-wave change flags
    float4   kbox[KDET];
    float    kar[KDET], ksc[KDET];
};

// rank-sort (O(n^2), fully parallel, zero dependent stages) -> scatter (box prefetched under rank loop)
// -> filter-vs-kept -> ST ballots -> Jacobi fixpoint -> parallel extract.
// Exact: unique fixpoint == serial greedy; serial fallback retained.
// PRE: S.keys[0..CAP) fully populated (real keys compacted at [0,M), PADKEY(t) elsewhere), barrier done.
__device__ __forceinline__ int process_chunk(ChunkShared& S, int tid, int M, int kc0,
                                             const float* __restrict__ boxes) {
    if (M <= 0) return kc0;                       // uniform across block
    const int lane = tid & 63, wid = tid >> 6;
    const uint64_t key = S.keys[tid];
    // ---- box prefetch: global load issues here, waitcnt lands after the rank loop ----
    const int n = (int)(key & 0xFFFFull);
    const int nc = n < N_ANCH ? n : N_ANCH - 1;   // pads carry tid in low bits: clamp for safe load
    const float4 mybox = *(const float4*)(boxes + (size_t)nc * 4);
    // ---- rank = #{j: key_j < key}; 256 broadcast LDS reads, compare-add; no barriers inside ----
    int rank = 0;
#pragma unroll 8
    for (int j = 0; j < CAP; j++) rank += (S.keys[j] < key) ? 1 : 0;
    // real keys < all pads => ranks of real keys occupy exactly [0, M)
    S.rbox[rank] = mybox;
    S.ra[rank] = (mybox.z - mybox.x) * (mybox.w - mybox.y);
    S.rs[rank] = __uint_as_float(~((uint32_t)(key >> 16)));
    __syncthreads();
    // ---- filter vs previously-kept boxes (exact chunk continuation) ----
    bool alive = (tid < M);
    if (alive && kc0 > 0) {
        float4 b = S.rbox[tid];
        float arb = S.ra[tid];
        for (int k2 = 0; k2 < kc0; k2++) {
            float4 kb = S.kbox[k2];
            float ix1 = fmaxf(kb.x, b.x), iy1 = fmaxf(kb.y, b.y);
            float ix2 = fminf(kb.z, b.z), iy2 = fminf(kb.w, b.w);
            float inter = fmaxf(ix2 - ix1, 0.0f) * fmaxf(iy2 - iy1, 0.0f);
            float iou = inter / (S.kar[k2] + arb - inter + 1e-8f);
            if (iou > 0.5f) { alive = false; break; }
        }
    }
    {
        uint64_t bal = __ballot(alive);
        if (lane == 0) S.lwbuf[wid] = bal;
    }
    __syncthreads();
    // ---- ST bitmatrix: column i = suppressors j<i, via ballots; (vw,ws) word-pairs over waves ----
    for (int p = wid; p < 10; p += 4) {
        const int vw = (int)((0x3333222110ull >> (4 * p)) & 0xF);   // victim word
        const int ws = (int)((0x3210210100ull >> (4 * p)) & 0xF);   // suppressor word (ws <= vw)
        const int i0 = vw << 6;
        if (i0 >= M) continue;
        const int i1 = min(M, i0 + 64);
        const int jj = (ws << 6) + lane;
        float4 bj = S.rbox[jj];                    // jj>=M possible only when ws==vw: masked by jj<i
        float arj = S.ra[jj];
        for (int i = i0; i < i1; i++) {
            bool bit = false;
            if (jj < i) {
                float4 bi = S.rbox[i];             // same-address LDS broadcast
                float ari = S.ra[i];
                float ix1 = fmaxf(bj.x, bi.x), iy1 = fmaxf(bj.y, bi.y);
                float ix2 = fminf(bj.z, bi.z), iy2 = fminf(bj.w, bi.w);
                float inter = fmaxf(ix2 - ix1, 0.0f) * fmaxf(iy2 - iy1, 0.0f);
                float iou = inter / (arj + ari - inter + 1e-8f);   // fp-add commutative: == ref order
                bit = iou > 0.5f;
            }
            uint64_t bb = __ballot(bit);
            if (lane == 0) S.smat[((size_t)i << 2) + ws] = bb;
        }
    }
    __syncthreads();
    // ---- my ST column into registers (words 0..wid written this chunk; others stale -> 0) ----
    uint64_t st0 = 0, st1 = 0, st2 = 0, st3 = 0;
    if (tid < M) {
        st0 = S.smat[((size_t)tid << 2) + 0];
        if (wid >= 1) st1 = S.smat[((size_t)tid << 2) + 1];
        if (wid >= 2) st2 = S.smat[((size_t)tid << 2) + 2];
        if (wid >= 3) st3 = S.smat[((size_t)tid << 2) + 3];
    }
    // ---- Jacobi to fixpoint: zero memory-dependent chain; ~2-4 rounds on sparse data ----
    bool kept = alive;
    bool converged = false;
    for (int it = 0; it < JMAX; it++) {
        uint64_t kb = __ballot(kept);
        if (lane == 0) S.s_kw[wid] = kb;
        __syncthreads();
        const uint64_t k0 = S.s_kw[0], k1 = S.s_kw[1], k2 = S.s_kw[2], k3 = S.s_kw[3];
        const bool sup = ((k0 & st0) | (k1 & st1) | (k2 & st2) | (k3 & st3)) != 0ull;
        const bool nk = alive && !sup;
        uint64_t cb = __ballot(nk != kept);
        if (lane == 0) S.s_cw[wid] = (cb != 0ull) ? 1 : 0;
        kept = nk;
        __syncthreads();
        if ((S.s_cw[0] | S.s_cw[1] | S.s_cw[2] | S.s_cw[3]) == 0) { converged = true; break; }
        // on break: s_kw holds ballot of pre-update kept == final kept (no change occurred)
    }
    if (!converged) {                              // exact serial fallback (pathological chains only)
        if (tid == 0) {
            uint64_t lv[4] = {S.lwbuf[0], S.lwbuf[1], S.lwbuf[2], S.lwbuf[3]};
            uint64_t kw[4] = {0, 0, 0, 0};
            for (int i = 0; i < M; i++) {
                const int w = i >> 6, b = i & 63;
                if (!((lv[w] >> b) & 1ull)) continue;
                const uint64_t* row = &S.smat[(size_t)i << 2];
                uint64_t sup = kw[0] & row[0];
                if (w >= 1) sup |= kw[1] & row[1];
                if (w >= 2) sup |= kw[2] & row[2];
                if (w >= 3) sup |= kw[3] & row[3];
                if (!sup) kw[w] |= 1ull << b;
            }
            S.s_kw[0] = kw[0]; S.s_kw[1] = kw[1]; S.s_kw[2] = kw[2]; S.s_kw[3] = kw[3];
        }
        __syncthreads();
    }
    // ---- parallel extraction in greedy (index) order ----
    const uint64_t k0 = S.s_kw[0], k1 = S.s_kw[1], k2 = S.s_kw[2], k3 = S.s_kw[3];
    const int total = __popcll(k0) + __popcll(k1) + __popcll(k2) + __popcll(k3);
    const uint64_t mykw = (wid == 0) ? k0 : (wid == 1) ? k1 : (wid == 2) ? k2 : k3;
    if (tid < M && ((mykw >> lane) & 1ull)) {
        int rk = __popcll(mykw & ((1ull << lane) - 1ull));
        if (wid > 0) rk += __popcll(k0);
        if (wid > 1) rk += __popcll(k1);
        if (wid > 2) rk += __popcll(k2);
        const int r = kc0 + rk;
        if (r < KDET) { S.kbox[r] = S.rbox[tid]; S.kar[r] = S.ra[tid]; S.ksc[r] = S.rs[tid]; }
    }
    __syncthreads();
    return min(kc0 + total, KDET);
}

// ---------------- 80 blocks: wave-prefix gather (2 sub-lists/thread) -> core; exact fallback ----------------
__global__ __launch_bounds__(TPB) void nms_final(const float* __restrict__ scores,
                                                 const float* __restrict__ boxes,
                                                 const uint64_t* __restrict__ list,
                                                 const int* __restrict__ subcnt,
                                                 int use_lists,
                                                 float* __restrict__ out) {
    const int c = blockIdx.x, tid = threadIdx.x;
    const int lane = tid & 63, wid = tid >> 6;
    __shared__ ChunkShared S;
    __shared__ int hist[NBINS];
    __shared__ int s_wtot[4];
    __shared__ int s_ov, s_cnt, s_lo;

    int kc = 0;
    bool fast = false;
    if (use_lists) {
        const int raw0 = subcnt[c * NBLK + tid];           // issue both loads first
        const int raw1 = subcnt[c * NBLK + TPB + tid];
        S.keys[tid] = PADKEY(tid);                         // pad everything; writers overwrite [0,M0)
        if (tid == 0) s_ov = 0;
        __syncthreads();
        if (raw0 > SUBCAP || raw1 > SUBCAP) atomicOr(&s_ov, 1);
        const int v0 = min(raw0, SUBCAP), v1 = min(raw1, SUBCAP);
        const int v = v0 + v1;
        int incl = v;                                      // wave-inclusive scan via shuffles
        for (int d = 1; d < 64; d <<= 1) {
            int o = __shfl_up(incl, d, 64);
            if (lane >= d) incl += o;
        }
        if (lane == 63) s_wtot[wid] = incl;
        __syncthreads();
        int woff = 0;
        for (int w = 0; w < wid; w++) woff += s_wtot[w];
        const int off = woff + incl - v;                   // exclusive offset (order arbitrary: sort fixes it)
        const int M0 = s_wtot[0] + s_wtot[1] + s_wtot[2] + s_wtot[3];
        fast = (s_ov == 0) && (M0 <= CAP);
        if (fast && v > 0) {
            const uint64_t* src0 = list + ((size_t)c * NBLK + tid) * SUBCAP;
            const uint64_t* src1 = list + ((size_t)c * NBLK + TPB + tid) * SUBCAP;
            for (int k = 0; k < v0; k++) S.keys[off + k] = src0[k];
            for (int k = 0; k < v1; k++) S.keys[off + v0 + k] = src1[k];
        }
        __syncthreads();
        if (fast) kc = process_chunk(S, tid, M0, 0, boxes);
    }
    if (kc < KDET) {
        // exact slow path: strided column reads; partition s <= THETA iff fast chunk consumed (s > THETA)
        const float hicut = fast ? THETA : 3.0e38f;
        if (!fast) kc = 0;
        for (int b = tid; b < NBINS; b += TPB) hist[b] = 0;
        __syncthreads();
        for (int n = tid; n < N_ANCH; n += TPB) {
            float s = scores[(size_t)n * NCLS + c];
            if (s > 0.05f && s <= hicut) {
                int b = (int)(s * 1024.0f);
                b = b < 0 ? 0 : (b > NBINS - 1 ? NBINS - 1 : b);
                atomicAdd(&hist[b], 1);
            }
        }
        __syncthreads();
        int hi = NBINS;
        while (hi > 0 && kc < KDET) {
            if (tid == 0) {
                int lo = hi, tot = 0;
                while (lo > 0 && tot + hist[lo - 1] <= CAP) { lo--; tot += hist[lo]; }
                if (lo == hi) lo = hi - 1;         // oversized single bin: truncate (not hit here)
                s_lo = lo; s_cnt = 0;
            }
            S.keys[tid] = PADKEY(tid);             // pad; collectors overwrite [0, M2)
            __syncthreads();
            const int lo = s_lo;
            for (int n = tid; n < N_ANCH; n += TPB) {
                float s = scores[(size_t)n * NCLS + c];
                if (s > 0.05f && s <= hicut) {
                    int b = (int)(s * 1024.0f);
                    b = b < 0 ? 0 : (b > NBINS - 1 ? NBINS - 1 : b);
                    if (b >= lo && b < hi) {
                        int p = atomicAdd(&s_cnt, 1);
                        if (p < CAP) {
                            uint32_t bits = __float_as_uint(s);
                            S.keys[p] = ((uint64_t)(~bits) << 16) | (uint64_t)n;
                        }
                    }
                }
            }
            __syncthreads();
            const int M2 = min(s_cnt, CAP);
            kc = process_chunk(S, tid, M2, kc, boxes);
            hi = lo;
        }
    }
    __syncthreads();

    // outputs: [scores | classes | boxes | valids] as float32
    float* o_sc = out;
    float* o_cl = out + NCLS * KDET;
    float* o_bx = out + 2 * NCLS * KDET;
    float* o_va = out + 6 * NCLS * KDET;
    for (int k = tid; k < KDET; k += TPB) {
        bool valid = k < kc;
        o_sc[c * KDET + k] = valid ? S.ksc[k] : 0.0f;
        o_cl[c * KDET + k] = (float)c;
        o_va[c * KDET + k] = valid ? 1.0f : 0.0f;
        float4 bo;
        if (valid) bo = S.kbox[k];
        else { bo.x = 0.0f; bo.y = 0.0f; bo.z = 0.0f; bo.w = 0.0f; }
        *(float4*)(o_bx + ((size_t)(c * KDET + k)) * 4) = bo;
    }
}

extern "C" void kernel_launch(void* const* d_in, const int* in_sizes, int n_in,
                              void* d_out, int out_size, void* d_ws, size_t ws_size,
                              hipStream_t stream) {
    const float* scores = (const float*)d_in[0];   // [N, C] f32
    const float* boxes  = (const float*)d_in[1];   // [N, 4] f32
    float* out = (float*)d_out;                    // 56000 f32: scores|classes|boxes|valids

    uint64_t* list   = (uint64_t*)d_ws;
    int*      subcnt = (int*)((char*)d_ws + SUBCNT_OFF);
    const int use_lists = (ws_size >= WS_NEED) ? 1 : 0;

    if (use_lists) {
        collect_kernel<<<NBLK, TPB, 0, stream>>>(scores, list, subcnt);
    }
    nms_final<<<NCLS, TPB, 0, stream>>>(scores, boxes, list, subcnt, use_lists, out);
}